// Round 12
// baseline (143.273 us; speedup 1.0000x reference)
//
#include <hip/hip_runtime.h>
#include <hip/hip_bf16.h>

// Grouped masked GEMM (DeepSeekMOE up/gate + down), fp32 in/out, bf16 MFMA.
// G=8, M=32. up/gate: K=4096,N=2816. down: K=1408,N=4096. out: [G,32,5632] f32.
//
// R11 = R10 (111.1us) + 2-wave shared-X blocks: BN=64, X bf16 tile staged into
// LDS once per BLOCK (halves X-side L2/L3 fabric traffic 270->135 MB) while
// keeping 6.75 waves/CU (864 x 128-thread blocks, 40 KB LDS, 4 blocks/CU =
// 160 KB all-resident). W path unchanged: gload_lds BK=128 (512B row-visits),
// source-granule XOR swizzle, per-iter full drain via __syncthreads.

#define G_    8
#define M_    32
#define KUG   4096
#define NUG   2816
#define KDN   1408
#define NDN   4096
#define NOUT  (NUG + NDN)      // 5632
#define BN    64               // per block (2 waves x 32 cols)
#define BK    128
#define UPT   (NUG / BN)       // 44 up units per group
#define DNT   (NDN / BN)       // 64 down units per group
#define UPG   (UPT + DNT)      // 108 units per group; grid = 864
#define XUG_E (G_ * M_ * KUG)  // 1048576
#define XDN_E (G_ * M_ * KDN)  // 360448
#define XBF_BYTES ((size_t)(XUG_E + XDN_E) * 2)

typedef __attribute__((ext_vector_type(8))) short bf16x8;
typedef __attribute__((ext_vector_type(4))) float f32x4;

typedef __attribute__((address_space(3))) float        lds_f32;
typedef const __attribute__((address_space(1))) float  gbl_f32;

// fp32 -> bf16 RNE via compiler (m240: don't hand-write cvt_pk asm).
__device__ __forceinline__ short f2bf(float x) {
  union { __hip_bfloat16 h; short s; } u;
  u.h = __hip_bfloat16(x);
  return u.s;
}
__device__ __forceinline__ bf16x8 cvt8(f32x4 lo, f32x4 hi) {
  bf16x8 o;
#pragma unroll
  for (int j = 0; j < 4; ++j) { o[j] = f2bf(lo[j]); o[4 + j] = f2bf(hi[j]); }
  return o;
}

// Prologue: f32 -> bf16 for both X arrays, one launch (688 blocks).
__global__ void cvt_x_kernel(const float* __restrict__ xu, const float* __restrict__ xd,
                             short* __restrict__ du, short* __restrict__ dd) {
  int i = blockIdx.x * 256 + threadIdx.x;
  const float* s; short* d;
  int j = i;
  if (i < XUG_E / 8) { s = xu; d = du; }
  else { s = xd; d = dd; j = i - XUG_E / 8; if (j >= XDN_E / 8) return; }
  f32x4 lo = *(const f32x4*)(s + (size_t)j * 8);
  f32x4 hi = *(const f32x4*)(s + (size_t)j * 8 + 4);
  *(bf16x8*)(d + (size_t)j * 8) = cvt8(lo, hi);
}

// ---------------- main kernel: 2 waves, shared X, BN=64 ----------------
__global__ __launch_bounds__(128, 2) void moe_masked_gemm_bf(
    const float* __restrict__ w_ug, const float* __restrict__ w_dn,
    const short* __restrict__ xbf_ug, const short* __restrict__ xbf_dn,
    const int* __restrict__ masked_m, float* __restrict__ out) {
  __shared__ __attribute__((aligned(16))) float wbuf[64 * BK];   // 32 KB
  __shared__ __attribute__((aligned(16))) short xsh[32 * BK];    // 8 KB bf16

  int b = blockIdx.x;
  int g = b & 7;                    // group -> XCD affinity
  int v = b >> 3;                   // unit slot 0..107
  // Bresenham 11:16 up/down interleave (44:64 = 4 exact periods of 27).
  int p = v / 27, s = v - p * 27;
  int ub = (s * 11 + 16) / 27;
  bool is_up = ((s * 11) % 27) < 11;

  const float* wg;
  const short* xq;
  int K, NIT, n0, colOff;
  if (is_up) {
    int u = p * 11 + ub;
    K = KUG; NIT = KUG / BK; n0 = u * BN; colOff = 0;          // 32 iters
    wg = w_ug + ((size_t)g * NUG + n0) * KUG;
    xq = xbf_ug + (size_t)g * M_ * KUG;
  } else {
    int d = p * 16 + (s - ub);
    K = KDN; NIT = KDN / BK; n0 = d * BN; colOff = NUG;        // 11 iters
    wg = w_dn + ((size_t)g * NDN + n0) * KDN;
    xq = xbf_dn + (size_t)g * M_ * KDN;
  }

  int mm = masked_m[g];
  int t  = threadIdx.x;
  int w  = t >> 6;                  // wave 0/1 -> cols w*32 .. w*32+31
  int r  = t & 15, q4 = (t >> 4) & 3;
  int sk = r & 7;                   // read-side swizzle key (rows = *16 + r)

  f32x4 acc[2][2];                  // [m-frag][n-frag]
#pragma unroll
  for (int mf = 0; mf < 2; ++mf)
#pragma unroll
    for (int nf = 0; nf < 2; ++nf) acc[mf][nf] = (f32x4){0.f, 0.f, 0.f, 0.f};

  if (mm != 0) {                    // block-uniform: no divergent barriers
    for (int it = 0; it < NIT; ++it) {
      int k0 = it * BK;

      // --- Stage W [64][128] f32: 2048 16B-granules / 128 thr = 16 instrs.
      // Instr i covers rows 4i..4i+3, 512B contiguous per row (R4 sweet spot).
      // LDS linear; bank-swizzle via source granule XOR (key row&7).
#pragma unroll
      for (int i = 0; i < 16; ++i) {
        int gid = i * 128 + t;
        int row = gid >> 5, q = gid & 31, qs = q ^ (row & 7);
        __builtin_amdgcn_global_load_lds(
            (gbl_f32*)(wg + (size_t)row * K + k0 + qs * 4),
            (lds_f32*)(wbuf + gid * 4), 16, 0, 0);
      }
      // --- Stage X bf16 [32][128]: 512 granules (8 shorts) / 128 thr = 4 instrs,
      // shared by both waves (the whole point: X global traffic once per block).
#pragma unroll
      for (int i = 0; i < 4; ++i) {
        int gid = i * 128 + t;
        int row = gid >> 4, q = gid & 15, qs = q ^ (row & 7);
        __builtin_amdgcn_global_load_lds(
            (gbl_f32*)(const void*)(xq + (size_t)row * K + k0 + qs * 8),
            (lds_f32*)(void*)(xsh + gid * 8), 16, 0, 0);
      }

      // Barrier 1: __syncthreads drains vmcnt(0)+lgkmcnt(0) then s_barrier ->
      // BOTH waves' DMAs are visible (cross-wave DMA completion is only
      // observable via the issuing wave's vmcnt, hence the full barrier).
      __syncthreads();

      // --- X fragments from LDS (swizzle-corrected 16B reads).
      bf16x8 xb[2][4];              // [m-frag][k-step]
#pragma unroll
      for (int mf = 0; mf < 2; ++mf)
#pragma unroll
        for (int ks = 0; ks < 4; ++ks) {
          int phys = (ks * 4 + q4) ^ sk;
          xb[mf][ks] = *(const bf16x8*)(xsh + (mf * 16 + r) * BK + phys * 8);
        }

      // --- W fragments + 16 MFMA (2 mf x 2 nf x 4 ks). W row = w*32+nf*16+r
      // (row&7 == sk for all, so one swizzle key works).
#pragma unroll
      for (int ks = 0; ks < 4; ++ks) {
        int g0 = (ks * 4 + q4) * 2;
        int o0 = ((g0 ^ sk) << 2), o1 = (((g0 + 1) ^ sk) << 2);
#pragma unroll
        for (int nf = 0; nf < 2; ++nf) {
          const float* rowp = wbuf + (size_t)(w * 32 + nf * 16 + r) * BK;
          bf16x8 bb = cvt8(*(const f32x4*)(rowp + o0), *(const f32x4*)(rowp + o1));
          acc[0][nf] = __builtin_amdgcn_mfma_f32_16x16x32_bf16(xb[0][ks], bb, acc[0][nf], 0, 0, 0);
          acc[1][nf] = __builtin_amdgcn_mfma_f32_16x16x32_bf16(xb[1][ks], bb, acc[1][nf], 0, 0, 0);
        }
      }

      // Barrier 2: both waves finished reading (lgkmcnt(0) implied) before the
      // next iteration's DMAs overwrite the shared buffers.
      __syncthreads();
    }
  }

  // Epilogue. C/D layout: col = lane&15, row = (lane>>4)*4 + i (m89-verified).
  // Lane stores cols n0 + w*32 + nf*16 + r, rows m = mf*16 + q4*4 + i; mask m>=mm.
  float* outg = out + (size_t)g * M_ * NOUT + colOff + n0 + w * 32;
#pragma unroll
  for (int i = 0; i < 4; ++i) {
    int m0 = q4 * 4 + i, m1 = 16 + m0;
    bool v0 = m0 < mm, v1 = m1 < mm;
#pragma unroll
    for (int nf = 0; nf < 2; ++nf) {
      outg[(size_t)m0 * NOUT + nf * 16 + r] = v0 ? acc[0][nf][i] : 0.f;
      outg[(size_t)m1 * NOUT + nf * 16 + r] = v1 ? acc[1][nf][i] : 0.f;
    }
  }
}

// ---------------- fallback (tiny ws): R10 f32-X single-wave kernel ----------
#define BN2   32
#define UPT2  (NUG / BN2)      // 88
#define UPG2  (UPT2 + NDN / BN2)  // 216
__global__ __launch_bounds__(64, 2) void moe_masked_gemm_f32(
    const float* __restrict__ x_ug, const float* __restrict__ w_ug,
    const float* __restrict__ x_dn, const float* __restrict__ w_dn,
    const int* __restrict__ masked_m, float* __restrict__ out) {
  __shared__ float wbuf[BN2 * BK];
  int b = blockIdx.x, g = b & 7, u = b >> 3;
  const float* wg; const float* xf;
  int K, NIT, n0, colOff;
  bool is_up = (u < UPT2);
  if (is_up) { K = KUG; NIT = KUG / BK; n0 = u * BN2; colOff = 0;
    wg = w_ug + ((size_t)g * NUG + n0) * KUG; xf = x_ug + (size_t)g * M_ * KUG;
  } else { int d = u - UPT2; K = KDN; NIT = KDN / BK; n0 = d * BN2; colOff = NUG;
    wg = w_dn + ((size_t)g * NDN + n0) * KDN; xf = x_dn + (size_t)g * M_ * KDN; }
  int mm = masked_m[g], t = threadIdx.x, r = t & 15, q4 = t >> 4, sk = r & 7;
  f32x4 acc[2][2];
#pragma unroll
  for (int mf = 0; mf < 2; ++mf)
#pragma unroll
    for (int nf = 0; nf < 2; ++nf) acc[mf][nf] = (f32x4){0.f, 0.f, 0.f, 0.f};
  if (mm != 0) {
    for (int it = 0; it < NIT; ++it) {
      int k0 = it * BK;
#pragma unroll
      for (int i = 0; i < 16; ++i) {
        int gid = i * 64 + t, row = gid >> 5, q = gid & 31, qs = q ^ (row & 7);
        __builtin_amdgcn_global_load_lds((gbl_f32*)(wg + (size_t)row * K + k0 + qs * 4),
                                         (lds_f32*)(wbuf + gid * 4), 16, 0, 0);
      }
      bf16x8 xb[2][4];
#pragma unroll
      for (int mf = 0; mf < 2; ++mf)
#pragma unroll
        for (int ks = 0; ks < 4; ++ks) {
          const float* xp = xf + (size_t)(mf * 16 + r) * K + k0 + ks * 32 + q4 * 8;
          xb[mf][ks] = cvt8(*(const f32x4*)xp, *(const f32x4*)(xp + 4));
        }
      asm volatile("s_waitcnt vmcnt(0)" ::: "memory");
      __builtin_amdgcn_sched_barrier(0);
#pragma unroll
      for (int ks = 0; ks < 4; ++ks) {
        int g0 = (ks * 4 + q4) * 2;
        int o0 = ((g0 ^ sk) << 2), o1 = (((g0 + 1) ^ sk) << 2);
#pragma unroll
        for (int nf = 0; nf < 2; ++nf) {
          const float* rowp = wbuf + (size_t)(nf * 16 + r) * BK;
          bf16x8 bb = cvt8(*(const f32x4*)(rowp + o0), *(const f32x4*)(rowp + o1));
          acc[0][nf] = __builtin_amdgcn_mfma_f32_16x16x32_bf16(xb[0][ks], bb, acc[0][nf], 0, 0, 0);
          acc[1][nf] = __builtin_amdgcn_mfma_f32_16x16x32_bf16(xb[1][ks], bb, acc[1][nf], 0, 0, 0);
        }
      }
    }
  }
  float* outg = out + (size_t)g * M_ * NOUT + colOff + n0;
#pragma unroll
  for (int i = 0; i < 4; ++i) {
    int m0 = q4 * 4 + i, m1 = 16 + m0;
    bool v0 = m0 < mm, v1 = m1 < mm;
#pragma unroll
    for (int nf = 0; nf < 2; ++nf) {
      outg[(size_t)m0 * NOUT + nf * 16 + r] = v0 ? acc[0][nf][i] : 0.f;
      outg[(size_t)m1 * NOUT + nf * 16 + r] = v1 ? acc[1][nf][i] : 0.f;
    }
  }
}

extern "C" void kernel_launch(void* const* d_in, const int* in_sizes, int n_in,
                              void* d_out, int out_size, void* d_ws, size_t ws_size,
                              hipStream_t stream) {
  const float* x_ug     = (const float*)d_in[0];
  const float* w_ug     = (const float*)d_in[1];
  const float* x_dn     = (const float*)d_in[2];
  const float* w_dn     = (const float*)d_in[3];
  const int*   masked_m = (const int*)d_in[4];
  float*       out      = (float*)d_out;

  short* xbf_ug = (short*)d_ws;
  short* xbf_dn = xbf_ug + XUG_E;

  if (ws_size >= XBF_BYTES) {
    int n8 = (XUG_E + XDN_E) / 8;
    cvt_x_kernel<<<dim3((n8 + 255) / 256), dim3(256), 0, stream>>>(
        x_ug, x_dn, xbf_ug, xbf_dn);
    moe_masked_gemm_bf<<<dim3(G_ * UPG), dim3(128), 0, stream>>>(
        w_ug, w_dn, xbf_ug, xbf_dn, masked_m, out);
  } else {
    moe_masked_gemm_f32<<<dim3(G_ * UPG2), dim3(64), 0, stream>>>(
        x_ug, w_ug, x_dn, w_dn, masked_m, out);
  }
}

// Round 13
// 139.320 us; speedup vs baseline: 1.0284x; 1.0284x over previous
//
#include <hip/hip_runtime.h>
#include <hip/hip_bf16.h>

// Grouped masked GEMM (DeepSeekMOE up/gate + down), fp32 in/out, bf16 MFMA.
// G=8, M=32. up/gate: K=4096,N=2816. down: K=1408,N=4096. out: [G,32,5632] f32.
//
// R12 = R10 byte-exact (best, 111.1us: n=32 one-wave units, 1728 all-resident
// blocks, W via global_load_lds BK=128 = 512B row-visits, source-granule XOR
// swizzle, per-iter vmcnt(0), XCD-affine g=b&7, X pre-converted bf16 in d_ws)
// + ONE change: Bresenham 11:16 up/down unit interleave so every CU's
// resident set carries the balanced W-byte share (~2.75 up + 4 down units)
// instead of all-up/all-down clusters (kills the up-CU overhang tail).

#define G_    8
#define M_    32
#define KUG   4096
#define NUG   2816
#define KDN   1408
#define NDN   4096
#define NOUT  (NUG + NDN)      // 5632
#define BN    32
#define BK    128
#define UPT   (NUG / BN)       // 88 up units per group
#define DNT   (NDN / BN)       // 128 down units per group
#define UPG   (UPT + DNT)      // 216 = 8 periods of 27 (11 up + 16 down)
#define XUG_E (G_ * M_ * KUG)  // 1048576
#define XDN_E (G_ * M_ * KDN)  // 360448
#define XBF_BYTES ((size_t)(XUG_E + XDN_E) * 2)

typedef __attribute__((ext_vector_type(8))) short bf16x8;
typedef __attribute__((ext_vector_type(4))) float f32x4;

typedef __attribute__((address_space(3))) float        lds_f32;
typedef const __attribute__((address_space(1))) float  gbl_f32;

// fp32 -> bf16 RNE via compiler (m240: don't hand-write cvt_pk asm).
__device__ __forceinline__ short f2bf(float x) {
  union { __hip_bfloat16 h; short s; } u;
  u.h = __hip_bfloat16(x);
  return u.s;
}
__device__ __forceinline__ bf16x8 cvt8(f32x4 lo, f32x4 hi) {
  bf16x8 o;
#pragma unroll
  for (int j = 0; j < 4; ++j) { o[j] = f2bf(lo[j]); o[4 + j] = f2bf(hi[j]); }
  return o;
}

// Prologue: f32 -> bf16 for both X arrays, one launch (688 blocks).
__global__ void cvt_x_kernel(const float* __restrict__ xu, const float* __restrict__ xd,
                             short* __restrict__ du, short* __restrict__ dd) {
  int i = blockIdx.x * 256 + threadIdx.x;
  const float* s; short* d;
  int j = i;
  if (i < XUG_E / 8) { s = xu; d = du; }
  else { s = xd; d = dd; j = i - XUG_E / 8; if (j >= XDN_E / 8) return; }
  f32x4 lo = *(const f32x4*)(s + (size_t)j * 8);
  f32x4 hi = *(const f32x4*)(s + (size_t)j * 8 + 4);
  *(bf16x8*)(d + (size_t)j * 8) = cvt8(lo, hi);
}

// Stage W tile [32 rows][BK=128 f32] via 16 gload_lds; instr i covers rows
// {2i,2i+1}, 512B contiguous per row (R4-proven sweet spot). LDS dest linear
// (gload_lds rule); bank-swizzle by source-granule XOR:
// LDS[row][q] = glob[row][q ^ (row&7)] (involution, re-applied on read).
__device__ __forceinline__ void stageW(const float* wg, float* wbuf, int K,
                                       int k0, int t) {
#pragma unroll
  for (int i = 0; i < 16; ++i) {
    int gid = i * 64 + t;
    int row = gid >> 5;           // 32 granules (16B) per row
    int q   = gid & 31;
    int qs  = q ^ (row & 7);
    __builtin_amdgcn_global_load_lds(
        (gbl_f32*)(wg + (size_t)row * K + k0 + qs * 4),
        (lds_f32*)(wbuf + gid * 4), 16, 0, 0);
  }
}

template<bool XBF>
__global__ __launch_bounds__(64, 2) void moe_masked_gemm(
    const float* __restrict__ x_ug, const float* __restrict__ w_ug,
    const float* __restrict__ x_dn, const float* __restrict__ w_dn,
    const short* __restrict__ xbf_ug, const short* __restrict__ xbf_dn,
    const int* __restrict__ masked_m, float* __restrict__ out) {
  __shared__ float wbuf[BN * BK];   // 16 KB -> all 1728 blocks co-resident

  int b = blockIdx.x;
  int g = b & 7;                    // group -> XCD affinity (R4 mapping)
  int v = b >> 3;                   // unit slot 0..215 within group
  // Bresenham 11:16 up/down interleave over 27-slot periods (8 periods =
  // 88 up + 128 down exactly). Each CU's ~6.75 consecutive slots then hold
  // the balanced W-byte mix instead of all-up or all-down clusters.
  int p = v / 27, s27 = v - p * 27;
  int ub = (s27 * 11 + 16) / 27;               // ups before slot s27 (+current)
  bool is_up = ((s27 * 11) % 27) < 11;

  const float* wg;
  const float* xf;
  const short* xq;
  int K, NIT, n0, colOff;
  if (is_up) {
    int u = p * 11 + ub;
    K = KUG; NIT = KUG / BK; n0 = u * BN; colOff = 0;          // 32 iters
    wg = w_ug + ((size_t)g * NUG + n0) * KUG;
    xf = x_ug + (size_t)g * M_ * KUG;
    xq = xbf_ug + (size_t)g * M_ * KUG;
  } else {
    int d = p * 16 + (s27 - ub);
    K = KDN; NIT = KDN / BK; n0 = d * BN; colOff = NUG;        // 11 iters
    wg = w_dn + ((size_t)g * NDN + n0) * KDN;
    xf = x_dn + (size_t)g * M_ * KDN;
    xq = xbf_dn + (size_t)g * M_ * KDN;
  }

  int mm = masked_m[g];
  int t  = threadIdx.x;
  int r  = t & 15, q4 = t >> 4;     // frag coords
  int sk = r & 7;                   // read-side swizzle key (== row&7 for lane's rows)

  f32x4 acc[2][2];                  // [m-frag][n-frag]
#pragma unroll
  for (int mf = 0; mf < 2; ++mf)
#pragma unroll
    for (int nf = 0; nf < 2; ++nf) acc[mf][nf] = (f32x4){0.f, 0.f, 0.f, 0.f};

  if (mm != 0) {                    // mm==0: skip ALL reads, epilogue writes zeros
    for (int it = 0; it < NIT; ++it) {
      int k0 = it * BK;

      // Issue the W DMAs first, then X loads ride behind them.
      stageW(wg, wbuf, K, k0, t);

      // X fragments (L2/L3-served). bf16 path: one 16B load, MFMA layout.
      bf16x8 xb[2][4];              // [m-frag][k-step]
      if constexpr (XBF) {
#pragma unroll
        for (int mf = 0; mf < 2; ++mf)
#pragma unroll
          for (int ks = 0; ks < 4; ++ks)
            xb[mf][ks] = *(const bf16x8*)(xq + (size_t)(mf * 16 + r) * K +
                                          k0 + ks * 32 + q4 * 8);
      } else {
#pragma unroll
        for (int mf = 0; mf < 2; ++mf)
#pragma unroll
          for (int ks = 0; ks < 4; ++ks) {
            const float* xp = xf + (size_t)(mf * 16 + r) * K + k0 + ks * 32 + q4 * 8;
            xb[mf][ks] = cvt8(*(const f32x4*)xp, *(const f32x4*)(xp + 4));
          }
      }

      // gload_lds -> ds_read dep is invisible to the compiler (rule #18).
      asm volatile("s_waitcnt vmcnt(0)" ::: "memory");
      __builtin_amdgcn_sched_barrier(0);

      // 4 k-steps x (2 m-frags x 2 n-frags) = 16 MFMA, swizzle-corrected reads.
#pragma unroll
      for (int ks = 0; ks < 4; ++ks) {
        int g0 = (ks * 4 + q4) * 2;
        int o0 = ((g0 ^ sk) << 2), o1 = (((g0 + 1) ^ sk) << 2);
#pragma unroll
        for (int nf = 0; nf < 2; ++nf) {
          const float* rowp = wbuf + (size_t)(nf * 16 + r) * BK;
          bf16x8 bb = cvt8(*(const f32x4*)(rowp + o0), *(const f32x4*)(rowp + o1));
          acc[0][nf] = __builtin_amdgcn_mfma_f32_16x16x32_bf16(xb[0][ks], bb, acc[0][nf], 0, 0, 0);
          acc[1][nf] = __builtin_amdgcn_mfma_f32_16x16x32_bf16(xb[1][ks], bb, acc[1][nf], 0, 0, 0);
        }
      }
      // Next iter's gload_lds can't pass this iter's ds_reads (same LDS buffer,
      // in-order wave) — R4-validated single-buffer reuse.
    }
  }

  // Epilogue. C/D layout: col = lane&15, row = (lane>>4)*4 + i (m89-verified).
  // Lane stores cols n0 + nf*16 + r for rows m = mf*16 + q4*4 + i; mask m >= mm.
  float* outg = out + (size_t)g * M_ * NOUT + colOff + n0;
#pragma unroll
  for (int i = 0; i < 4; ++i) {
    int m0 = q4 * 4 + i, m1 = 16 + m0;
    bool v0 = m0 < mm, v1 = m1 < mm;
#pragma unroll
    for (int nf = 0; nf < 2; ++nf) {
      outg[(size_t)m0 * NOUT + nf * 16 + r] = v0 ? acc[0][nf][i] : 0.f;
      outg[(size_t)m1 * NOUT + nf * 16 + r] = v1 ? acc[1][nf][i] : 0.f;
    }
  }
}

extern "C" void kernel_launch(void* const* d_in, const int* in_sizes, int n_in,
                              void* d_out, int out_size, void* d_ws, size_t ws_size,
                              hipStream_t stream) {
  const float* x_ug     = (const float*)d_in[0];
  const float* w_ug     = (const float*)d_in[1];
  const float* x_dn     = (const float*)d_in[2];
  const float* w_dn     = (const float*)d_in[3];
  const int*   masked_m = (const int*)d_in[4];
  float*       out      = (float*)d_out;

  short* xbf_ug = (short*)d_ws;
  short* xbf_dn = xbf_ug + XUG_E;

  if (ws_size >= XBF_BYTES) {
    int n8 = (XUG_E + XDN_E) / 8;
    cvt_x_kernel<<<dim3((n8 + 255) / 256), dim3(256), 0, stream>>>(
        x_ug, x_dn, xbf_ug, xbf_dn);
    moe_masked_gemm<true><<<dim3(G_ * UPG), dim3(64), 0, stream>>>(
        x_ug, w_ug, x_dn, w_dn, xbf_ug, xbf_dn, masked_m, out);
  } else {
    moe_masked_gemm<false><<<dim3(G_ * UPG), dim3(64), 0, stream>>>(
        x_ug, w_ug, x_dn, w_dn, xbf_ug, xbf_dn, masked_m, out);
  }
}

// Round 14
// 113.424 us; speedup vs baseline: 1.2632x; 1.2283x over previous
//
#include <hip/hip_runtime.h>
#include <hip/hip_bf16.h>

// Grouped masked GEMM (DeepSeekMOE up/gate + down), fp32 in/out, bf16 MFMA.
// G=8, M=32. up/gate: K=4096,N=2816. down: K=1408,N=4096. out: [G,32,5632] f32.
//
// R13 = R10 byte-exact revert (proven best, 111.1us). R12's A/B proved the
// sequential unit ordering (ups 0..87 then downs 88..215 per group) is worth
// ~28us vs interleaved: consecutive blocks stream ADJACENT W panels -> DRAM
// page/bank locality + contiguous per-XCD L2 sweep. Do not interleave.
// Structure: 1728 one-wave all-resident blocks (16KB LDS, 6.75 waves/CU),
// W via global_load_lds BK=128 (512B row-visits, the measured DRAM optimum),
// source-granule XOR swizzle, per-iter vmcnt(0) drain (counted-vmcnt pipelines
// measured worse), X pre-converted bf16 in d_ws (halves X fabric traffic),
// XCD-affine g = b&7.

#define G_    8
#define M_    32
#define KUG   4096
#define NUG   2816
#define KDN   1408
#define NDN   4096
#define NOUT  (NUG + NDN)      // 5632
#define BN    32
#define BK    128
#define UPT   (NUG / BN)       // 88 up units per group
#define DNT   (NDN / BN)       // 128 down units per group
#define UPG   (UPT + DNT)      // 216 units per group; grid = 1728
#define XUG_E (G_ * M_ * KUG)  // 1048576
#define XDN_E (G_ * M_ * KDN)  // 360448
#define XBF_BYTES ((size_t)(XUG_E + XDN_E) * 2)

typedef __attribute__((ext_vector_type(8))) short bf16x8;
typedef __attribute__((ext_vector_type(4))) float f32x4;

typedef __attribute__((address_space(3))) float        lds_f32;
typedef const __attribute__((address_space(1))) float  gbl_f32;

// fp32 -> bf16 RNE via compiler (m240: don't hand-write cvt_pk asm).
__device__ __forceinline__ short f2bf(float x) {
  union { __hip_bfloat16 h; short s; } u;
  u.h = __hip_bfloat16(x);
  return u.s;
}
__device__ __forceinline__ bf16x8 cvt8(f32x4 lo, f32x4 hi) {
  bf16x8 o;
#pragma unroll
  for (int j = 0; j < 4; ++j) { o[j] = f2bf(lo[j]); o[4 + j] = f2bf(hi[j]); }
  return o;
}

// Prologue: f32 -> bf16 for both X arrays, one launch (688 blocks).
__global__ void cvt_x_kernel(const float* __restrict__ xu, const float* __restrict__ xd,
                             short* __restrict__ du, short* __restrict__ dd) {
  int i = blockIdx.x * 256 + threadIdx.x;
  const float* s; short* d;
  int j = i;
  if (i < XUG_E / 8) { s = xu; d = du; }
  else { s = xd; d = dd; j = i - XUG_E / 8; if (j >= XDN_E / 8) return; }
  f32x4 lo = *(const f32x4*)(s + (size_t)j * 8);
  f32x4 hi = *(const f32x4*)(s + (size_t)j * 8 + 4);
  *(bf16x8*)(d + (size_t)j * 8) = cvt8(lo, hi);
}

// Stage W tile [32 rows][BK=128 f32] via 16 gload_lds; instr i covers rows
// {2i,2i+1}, 512B contiguous per row (measured DRAM-visit optimum). LDS dest
// linear (gload_lds rule); bank-swizzle by source-granule XOR:
// LDS[row][q] = glob[row][q ^ (row&7)] (involution, re-applied on read).
__device__ __forceinline__ void stageW(const float* wg, float* wbuf, int K,
                                       int k0, int t) {
#pragma unroll
  for (int i = 0; i < 16; ++i) {
    int gid = i * 64 + t;
    int row = gid >> 5;           // 32 granules (16B) per row
    int q   = gid & 31;
    int qs  = q ^ (row & 7);
    __builtin_amdgcn_global_load_lds(
        (gbl_f32*)(wg + (size_t)row * K + k0 + qs * 4),
        (lds_f32*)(wbuf + gid * 4), 16, 0, 0);
  }
}

template<bool XBF>
__global__ __launch_bounds__(64, 2) void moe_masked_gemm(
    const float* __restrict__ x_ug, const float* __restrict__ w_ug,
    const float* __restrict__ x_dn, const float* __restrict__ w_dn,
    const short* __restrict__ xbf_ug, const short* __restrict__ xbf_dn,
    const int* __restrict__ masked_m, float* __restrict__ out) {
  __shared__ float wbuf[BN * BK];   // 16 KB -> all 1728 blocks co-resident

  int b = blockIdx.x;
  int g = b & 7;                    // group -> XCD affinity
  int u = b >> 3;                   // SEQUENTIAL unit order: [0,88) up, [88,216) down
                                    // (R12 A/B: interleaving costs ~28us — keep sequential)

  const float* wg;
  const float* xf;
  const short* xq;
  int K, NIT, n0, colOff;
  bool is_up = (u < UPT);
  if (is_up) {
    K = KUG; NIT = KUG / BK; n0 = u * BN; colOff = 0;          // 32 iters
    wg = w_ug + ((size_t)g * NUG + n0) * KUG;
    xf = x_ug + (size_t)g * M_ * KUG;
    xq = xbf_ug + (size_t)g * M_ * KUG;
  } else {
    int d = u - UPT;
    K = KDN; NIT = KDN / BK; n0 = d * BN; colOff = NUG;        // 11 iters
    wg = w_dn + ((size_t)g * NDN + n0) * KDN;
    xf = x_dn + (size_t)g * M_ * KDN;
    xq = xbf_dn + (size_t)g * M_ * KDN;
  }

  int mm = masked_m[g];
  int t  = threadIdx.x;
  int r  = t & 15, q4 = t >> 4;     // frag coords
  int sk = r & 7;                   // read-side swizzle key (== row&7 for lane's rows)

  f32x4 acc[2][2];                  // [m-frag][n-frag]
#pragma unroll
  for (int mf = 0; mf < 2; ++mf)
#pragma unroll
    for (int nf = 0; nf < 2; ++nf) acc[mf][nf] = (f32x4){0.f, 0.f, 0.f, 0.f};

  if (mm != 0) {                    // mm==0: skip ALL reads, epilogue writes zeros
    for (int it = 0; it < NIT; ++it) {
      int k0 = it * BK;

      // Issue the W DMAs first, then X loads ride behind them.
      stageW(wg, wbuf, K, k0, t);

      // X fragments (L2/L3-served). bf16 path: one 16B load, MFMA layout.
      bf16x8 xb[2][4];              // [m-frag][k-step]
      if constexpr (XBF) {
#pragma unroll
        for (int mf = 0; mf < 2; ++mf)
#pragma unroll
          for (int ks = 0; ks < 4; ++ks)
            xb[mf][ks] = *(const bf16x8*)(xq + (size_t)(mf * 16 + r) * K +
                                          k0 + ks * 32 + q4 * 8);
      } else {
#pragma unroll
        for (int mf = 0; mf < 2; ++mf)
#pragma unroll
          for (int ks = 0; ks < 4; ++ks) {
            const float* xp = xf + (size_t)(mf * 16 + r) * K + k0 + ks * 32 + q4 * 8;
            xb[mf][ks] = cvt8(*(const f32x4*)xp, *(const f32x4*)(xp + 4));
          }
      }

      // gload_lds -> ds_read dep is invisible to the compiler (rule #18).
      asm volatile("s_waitcnt vmcnt(0)" ::: "memory");
      __builtin_amdgcn_sched_barrier(0);

      // 4 k-steps x (2 m-frags x 2 n-frags) = 16 MFMA, swizzle-corrected reads.
#pragma unroll
      for (int ks = 0; ks < 4; ++ks) {
        int g0 = (ks * 4 + q4) * 2;
        int o0 = ((g0 ^ sk) << 2), o1 = (((g0 + 1) ^ sk) << 2);
#pragma unroll
        for (int nf = 0; nf < 2; ++nf) {
          const float* rowp = wbuf + (size_t)(nf * 16 + r) * BK;
          bf16x8 bb = cvt8(*(const f32x4*)(rowp + o0), *(const f32x4*)(rowp + o1));
          acc[0][nf] = __builtin_amdgcn_mfma_f32_16x16x32_bf16(xb[0][ks], bb, acc[0][nf], 0, 0, 0);
          acc[1][nf] = __builtin_amdgcn_mfma_f32_16x16x32_bf16(xb[1][ks], bb, acc[1][nf], 0, 0, 0);
        }
      }
      // Next iter's gload_lds can't pass this iter's ds_reads (same LDS buffer,
      // in-order wave) — validated single-buffer reuse.
    }
  }

  // Epilogue. C/D layout: col = lane&15, row = (lane>>4)*4 + i (m89-verified).
  // Lane stores cols n0 + nf*16 + r for rows m = mf*16 + q4*4 + i; mask m >= mm.
  float* outg = out + (size_t)g * M_ * NOUT + colOff + n0;
#pragma unroll
  for (int i = 0; i < 4; ++i) {
    int m0 = q4 * 4 + i, m1 = 16 + m0;
    bool v0 = m0 < mm, v1 = m1 < mm;
#pragma unroll
    for (int nf = 0; nf < 2; ++nf) {
      outg[(size_t)m0 * NOUT + nf * 16 + r] = v0 ? acc[0][nf][i] : 0.f;
      outg[(size_t)m1 * NOUT + nf * 16 + r] = v1 ? acc[1][nf][i] : 0.f;
    }
  }
}

extern "C" void kernel_launch(void* const* d_in, const int* in_sizes, int n_in,
                              void* d_out, int out_size, void* d_ws, size_t ws_size,
                              hipStream_t stream) {
  const float* x_ug     = (const float*)d_in[0];
  const float* w_ug     = (const float*)d_in[1];
  const float* x_dn     = (const float*)d_in[2];
  const float* w_dn     = (const float*)d_in[3];
  const int*   masked_m = (const int*)d_in[4];
  float*       out      = (float*)d_out;

  short* xbf_ug = (short*)d_ws;
  short* xbf_dn = xbf_ug + XUG_E;

  if (ws_size >= XBF_BYTES) {
    int n8 = (XUG_E + XDN_E) / 8;
    cvt_x_kernel<<<dim3((n8 + 255) / 256), dim3(256), 0, stream>>>(
        x_ug, x_dn, xbf_ug, xbf_dn);
    moe_masked_gemm<true><<<dim3(G_ * UPG), dim3(64), 0, stream>>>(
        x_ug, w_ug, x_dn, w_dn, xbf_ug, xbf_dn, masked_m, out);
  } else {
    moe_masked_gemm<false><<<dim3(G_ * UPG), dim3(64), 0, stream>>>(
        x_ug, w_ug, x_dn, w_dn, xbf_ug, xbf_dn, masked_m, out);
  }
}